// Round 2
// baseline (157.945 us; speedup 1.0000x reference)
//
#include <hip/hip_runtime.h>
#include <stdint.h>

typedef __bf16 bf16;
typedef bf16 bf16x8 __attribute__((ext_vector_type(8)));
typedef float f32x4 __attribute__((ext_vector_type(4)));
typedef unsigned short u16x8 __attribute__((ext_vector_type(8)));

__device__ __forceinline__ unsigned short f2bfu(float f) {
    union { bf16 h; unsigned short u; } x;
    x.h = (bf16)f;
    return x.u;
}
__device__ __forceinline__ float bfu2f(unsigned short u) {
    union { unsigned int i; float f; } x;
    x.i = ((unsigned int)u) << 16;
    return x.f;
}
__device__ __forceinline__ unsigned int pack2bf(float a, float b) {
    union { bf16 h[2]; unsigned int u; } x;
    x.h[0] = (bf16)a; x.h[1] = (bf16)b;
    return x.u;
}

// global -> LDS async copy, 16B per lane. LDS dest must be wave-uniform.
__device__ __forceinline__ void gld_lds16(const void* g, void* l) {
    __builtin_amdgcn_global_load_lds(
        (const __attribute__((address_space(1))) unsigned int*)(uintptr_t)g,
        (__attribute__((address_space(3))) unsigned int*)(unsigned int)(uintptr_t)l,
        16, 0, 0);
}

// ---------------- cast fp32 -> bf16, 8 elems/thread ----------------
__global__ void cast_bf16_kernel(const float* __restrict__ in,
                                 unsigned short* __restrict__ out, int n8) {
    int i = blockIdx.x * blockDim.x + threadIdx.x;
    if (i >= n8) return;
    const f32x4* p = (const f32x4*)(in + (size_t)i * 8);
    f32x4 a = p[0], b = p[1];
    u16x8 o;
    o[0]=f2bfu(a[0]); o[1]=f2bfu(a[1]); o[2]=f2bfu(a[2]); o[3]=f2bfu(a[3]);
    o[4]=f2bfu(b[0]); o[5]=f2bfu(b[1]); o[6]=f2bfu(b[2]); o[7]=f2bfu(b[3]);
    *(u16x8*)(out + (size_t)i * 8) = o;
}

// ---------------- RoPE in-place on q,k sections of qkv [4096][3072] bf16 ----
// thread handles 8 (x1,x2) pairs; q additionally scaled by 0.125 (exact).
__global__ void rope_kernel(unsigned short* __restrict__ qkv,
                            const float* __restrict__ cosp,
                            const float* __restrict__ sinp) {
    int tid = blockIdx.x * blockDim.x + threadIdx.x;   // 524288 total
    int i8  = tid & 3;
    int h   = (tid >> 2) & 15;
    int sel = (tid >> 6) & 1;
    int n   = (tid >> 7) & 2047;
    int b   = tid >> 18;
    size_t base = ((size_t)(b*2048 + n))*3072 + sel*1024 + h*64 + i8*8;
    u16x8 x1 = *(u16x8*)(qkv + base);
    u16x8 x2 = *(u16x8*)(qkv + base + 32);
    const f32x4* cp = (const f32x4*)(cosp + n*64 + i8*8);
    const f32x4* sp = (const f32x4*)(sinp + n*64 + i8*8);
    f32x4 c0 = cp[0], c1 = cp[1], s0 = sp[0], s1 = sp[1];
    float scale = sel ? 1.0f : 0.125f;
    u16x8 o1, o2;
#pragma unroll
    for (int j = 0; j < 8; j++) {
        float cc = (j < 4) ? c0[j] : c1[j-4];
        float ss = (j < 4) ? s0[j] : s1[j-4];
        float a = bfu2f(x1[j]), d = bfu2f(x2[j]);
        o1[j] = f2bfu((a*cc - d*ss) * scale);
        o2[j] = f2bfu((d*cc + a*ss) * scale);
    }
    *(u16x8*)(qkv + base)      = o1;
    *(u16x8*)(qkv + base + 32) = o2;
}

// ---------------- bf16 GEMM: C[M,N] = A[M,K] * B[N,K]^T (both K-contig) -----
// m97 structure: 128x128 tile, BK=32, 4 waves, global_load_lds w=16.
template<int OUT_F32>
__global__ __launch_bounds__(256, 2) void gemm_bt(
    const unsigned short* __restrict__ A, const unsigned short* __restrict__ B,
    void* __restrict__ Cp, const float* __restrict__ bias,
    int M, int N, int K)
{
    __shared__ __align__(16) unsigned short As[128*32];
    __shared__ __align__(16) unsigned short Bs[128*32];
    int nwg  = gridDim.x * gridDim.y;
    int orig = blockIdx.y * gridDim.x + blockIdx.x;
    int qq = nwg >> 3, rr = nwg & 7;
    int xcd = orig & 7, idx = orig >> 3;
    int wg = (xcd < rr) ? (xcd*(qq+1) + idx) : (rr*(qq+1) + (xcd-rr)*qq + idx);
    int bx = wg % gridDim.x, by = wg / gridDim.x;
    int m0 = by * 128, n0 = bx * 128;
    int t = threadIdx.x;
    int w = t >> 6, l = t & 63;
    int c = l & 15, g = l >> 4;
    int wm = (w >> 1) * 64, wn = (w & 1) * 64;

    f32x4 acc[4][4];
#pragma unroll
    for (int i = 0; i < 4; i++)
#pragma unroll
        for (int j = 0; j < 4; j++) acc[i][j] = f32x4{0.f,0.f,0.f,0.f};

    int nkt = K >> 5;
    for (int kt = 0; kt < nkt; ++kt) {
        int k0 = kt << 5;
#pragma unroll
        for (int r2 = 0; r2 < 2; ++r2) {
            int xb = w*2048 + r2*1024;        // byte base of wave chunk
            int x  = xb + l*16;               // per-lane byte
            int row  = x >> 6;                // 64B per row (32 bf16)
            int colu = (x & 63) >> 1;         // ushort col
            gld_lds16(A + (size_t)(m0+row)*K + k0 + colu, (void*)(As + (xb >> 1)));
            gld_lds16(B + (size_t)(n0+row)*K + k0 + colu, (void*)(Bs + (xb >> 1)));
        }
        __syncthreads();
        const unsigned short* Ab = As + wm*32;
        const unsigned short* Bb = Bs + wn*32;
        bf16x8 af[4], bfr[4];
#pragma unroll
        for (int i = 0; i < 4; i++) af[i]  = *(const bf16x8*)(Ab + (i*16+c)*32 + g*8);
#pragma unroll
        for (int i = 0; i < 4; i++) bfr[i] = *(const bf16x8*)(Bb + (i*16+c)*32 + g*8);
#pragma unroll
        for (int i = 0; i < 4; i++)
#pragma unroll
            for (int j = 0; j < 4; j++)
                acc[i][j] = __builtin_amdgcn_mfma_f32_16x16x32_bf16(af[i], bfr[j], acc[i][j], 0, 0, 0);
        __syncthreads();
    }
#pragma unroll
    for (int i = 0; i < 4; i++)
#pragma unroll
        for (int j = 0; j < 4; j++)
#pragma unroll
            for (int e = 0; e < 4; e++) {
                int row = m0 + wm + i*16 + g*4 + e;
                int col = n0 + wn + j*16 + c;
                float v = acc[i][j][e];
                if (bias) v += bias[col];
                if (OUT_F32) ((float*)Cp)[(size_t)row*N + col] = v;
                else ((unsigned short*)Cp)[(size_t)row*N + col] = f2bfu(v);
            }
}

// ---------------- flash attention (no-max online softmax) -------------------
// grid (16 q-tiles, 32 bh). block 256 = 4 waves; wave owns 32 q rows.
// S^T = mfma(K, Q) so P^T feeds PV B-frag via shuffles; out^T = mfma(V^T, P^T).
__global__ __launch_bounds__(256, 2) void attn_kernel(
    const unsigned short* __restrict__ qkv, unsigned short* __restrict__ outp)
{
    __shared__ __align__(16) unsigned short Ks[64*64];  // K tile, swizzled storage
    __shared__ __align__(16) unsigned short Vt[64*64];  // V^T tile, swizzled
    int bh = blockIdx.y;
    int b = bh >> 4, h = bh & 15;
    int q0 = blockIdx.x << 7;
    int t = threadIdx.x;
    int w = t >> 6, l = t & 63;
    int c = l & 15, g = l >> 4;
    int qw = q0 + w*32;
    size_t bh_base = ((size_t)b*2048)*3072 + (size_t)h*64;

    // Q fragments (B-operand layout): qf[mi][dt] = Q[qw+mi*16+c][dt*32+g*8..+7]
    bf16x8 qf[2][2];
#pragma unroll
    for (int mi = 0; mi < 2; mi++)
#pragma unroll
        for (int dt = 0; dt < 2; dt++)
            qf[mi][dt] = *(const bf16x8*)(qkv + bh_base + (size_t)(qw + mi*16 + c)*3072 + dt*32 + g*8);

    f32x4 oacc[4][2];
#pragma unroll
    for (int ni = 0; ni < 4; ni++)
#pragma unroll
        for (int mi = 0; mi < 2; mi++) oacc[ni][mi] = f32x4{0.f,0.f,0.f,0.f};
    float lsum[2] = {0.f, 0.f};

    for (int kvt = 0; kvt < 32; ++kvt) {
        int kv0 = kvt << 6;
        // stage K tile via global_load_lds, source pre-swizzled (read-side XOR)
#pragma unroll
        for (int r2 = 0; r2 < 2; ++r2) {
            int xb = w*2048 + r2*1024;
            int x  = xb + l*16;
            int row  = x >> 7;                 // 128B rows
            int colb = x & 127;
            int scolb = colb ^ ((row & 7) << 4);
            gld_lds16(qkv + bh_base + 1024 + (size_t)(kv0 + row)*3072 + (scolb >> 1),
                      (void*)(Ks + (xb >> 1)));
        }
        // stage V^T (reg transpose), swizzled to kill write/read bank conflicts
        {
            int p  = t >> 3;
            int hb = (t & 7) << 3;
            const unsigned short* src = qkv + bh_base + 2048 + (size_t)(kv0 + 2*p)*3072 + hb;
            u16x8 v0 = *(const u16x8*)src;
            u16x8 v1 = *(const u16x8*)(src + 3072);
#pragma unroll
            for (int e = 0; e < 8; e++) {
                int hd = hb + e;
                int colb = (4*p) ^ ((((hd) ^ (hd >> 3)) & 7) << 4);
                *(unsigned int*)((char*)Vt + hd*128 + colb) =
                    (unsigned int)v0[e] | ((unsigned int)v1[e] << 16);
            }
        }
        __syncthreads();

        // S^T[kv][qrow] = K * Q^T   (16 MFMA)
        f32x4 st[4][2];
#pragma unroll
        for (int nt = 0; nt < 4; nt++)
#pragma unroll
            for (int mi = 0; mi < 2; mi++) st[nt][mi] = f32x4{0.f,0.f,0.f,0.f};
#pragma unroll
        for (int nt = 0; nt < 4; ++nt) {
            int row = nt*16 + c;
            int sw = (row & 7) << 4;
            bf16x8 kf0 = *(const bf16x8*)((const char*)Ks + row*128 + ((g*16) ^ sw));
            bf16x8 kf1 = *(const bf16x8*)((const char*)Ks + row*128 + ((64 + g*16) ^ sw));
#pragma unroll
            for (int mi = 0; mi < 2; mi++) {
                st[nt][mi] = __builtin_amdgcn_mfma_f32_16x16x32_bf16(kf0, qf[mi][0], st[nt][mi], 0,0,0);
                st[nt][mi] = __builtin_amdgcn_mfma_f32_16x16x32_bf16(kf1, qf[mi][1], st[nt][mi], 0,0,0);
            }
        }
        // P = exp(S) (no max subtraction: |s| <= ~12, fp32-safe), pack bf16 pairs
        unsigned int pw[4][2][2];
#pragma unroll
        for (int nt = 0; nt < 4; nt++)
#pragma unroll
            for (int mi = 0; mi < 2; mi++) {
                float p0 = __expf(st[nt][mi][0]);
                float p1 = __expf(st[nt][mi][1]);
                float p2 = __expf(st[nt][mi][2]);
                float p3 = __expf(st[nt][mi][3]);
                lsum[mi] += (p0 + p1) + (p2 + p3);
                pw[nt][mi][0] = pack2bf(p0, p1);
                pw[nt][mi][1] = pack2bf(p2, p3);
            }
        // PV: out^T += V^T * P^T  (P^T B-frags assembled via shuffles)
#pragma unroll
        for (int ktp = 0; ktp < 2; ++ktp) {
            bf16x8 pf[2];
#pragma unroll
            for (int mi = 0; mi < 2; mi++) {
                union { unsigned int u[4]; bf16x8 v; } pb;
#pragma unroll
                for (int q2 = 0; q2 < 4; q2++) {
                    int ls = ((2*(g & 1) + (q2 >> 1)) << 4) + c;
                    unsigned int va = (unsigned int)__shfl((int)pw[2*ktp][mi][q2 & 1], ls, 64);
                    unsigned int vb = (unsigned int)__shfl((int)pw[2*ktp+1][mi][q2 & 1], ls, 64);
                    pb.u[q2] = (g & 2) ? vb : va;
                }
                pf[mi] = pb.v;
            }
#pragma unroll
            for (int ni = 0; ni < 4; ni++) {
                int hd = ni*16 + c;
                int sw2 = ((hd ^ (hd >> 3)) & 7) << 4;
                bf16x8 vf = *(const bf16x8*)((const char*)Vt + hd*128 + (((ktp << 6) + (g << 4)) ^ sw2));
#pragma unroll
                for (int mi = 0; mi < 2; mi++)
                    oacc[ni][mi] = __builtin_amdgcn_mfma_f32_16x16x32_bf16(vf, pf[mi], oacc[ni][mi], 0,0,0);
            }
        }
        __syncthreads();
    }
    // finalize: row sums across lane groups, divide, store bf16 out [B,N,H*HD]
#pragma unroll
    for (int mi = 0; mi < 2; mi++) {
        lsum[mi] += __shfl_xor(lsum[mi], 16, 64);
        lsum[mi] += __shfl_xor(lsum[mi], 32, 64);
    }
#pragma unroll
    for (int ni = 0; ni < 4; ni++)
#pragma unroll
        for (int mi = 0; mi < 2; mi++)
#pragma unroll
            for (int e = 0; e < 4; e++) {
                float v = oacc[ni][mi][e] / lsum[mi];
                size_t orow = (size_t)(b*2048 + qw + mi*16 + c);
                outp[orow*1024 + h*64 + ni*16 + g*4 + e] = f2bfu(v);
            }
}

// ---------------- launch ----------------------------------------------------
extern "C" void kernel_launch(void* const* d_in, const int* in_sizes, int n_in,
                              void* d_out, int out_size, void* d_ws, size_t ws_size,
                              hipStream_t stream) {
    const float* x      = (const float*)d_in[0];
    const float* cosp   = (const float*)d_in[1];
    const float* sinp   = (const float*)d_in[2];
    const float* qkv_w  = (const float*)d_in[3];
    const float* proj_w = (const float*)d_in[4];
    const float* proj_b = (const float*)d_in[5];

    char* ws = (char*)d_ws;
    // ws layout (40 MB total):
    // [0,8MB)   xb   : x in bf16 [4096][1024]   (reused as attn output later)
    // [8,14MB)  wqkvb: qkv_w bf16 [3072][1024]
    // [14,16MB) wprojb: proj_w bf16 [1024][1024]
    // [16,40MB) qkvb : qkv bf16 [4096][3072]
    unsigned short* xb     = (unsigned short*)(ws);
    unsigned short* wqkvb  = (unsigned short*)(ws + (size_t)(8u << 20));
    unsigned short* wprojb = (unsigned short*)(ws + (size_t)(14u << 20));
    unsigned short* qkvb   = (unsigned short*)(ws + (size_t)(16u << 20));
    unsigned short* attno  = xb;

    cast_bf16_kernel<<<2048, 256, 0, stream>>>(x, xb, 524288);
    cast_bf16_kernel<<<1536, 256, 0, stream>>>(qkv_w, wqkvb, 393216);
    cast_bf16_kernel<<<512, 256, 0, stream>>>(proj_w, wprojb, 131072);

    gemm_bt<0><<<dim3(24, 32), 256, 0, stream>>>(xb, wqkvb, (void*)qkvb, nullptr, 4096, 3072, 1024);
    rope_kernel<<<2048, 256, 0, stream>>>(qkvb, cosp, sinp);
    attn_kernel<<<dim3(16, 32), 256, 0, stream>>>(qkvb, attno);
    gemm_bt<1><<<dim3(8, 32), 256, 0, stream>>>(attno, wprojb, d_out, proj_b, 4096, 1024, 1024);
}

// Round 6
// 145.183 us; speedup vs baseline: 1.0879x; 1.0879x over previous
//
#include <hip/hip_runtime.h>
#include <stdint.h>

typedef __bf16 bf16;
typedef bf16 bf16x8 __attribute__((ext_vector_type(8)));
typedef float f32x4 __attribute__((ext_vector_type(4)));
typedef float f32x16 __attribute__((ext_vector_type(16)));
typedef unsigned short u16x8 __attribute__((ext_vector_type(8)));
typedef unsigned short u16x4 __attribute__((ext_vector_type(4)));

__device__ __forceinline__ unsigned short f2bfu(float f) {
    union { bf16 h; unsigned short u; } x;
    x.h = (bf16)f;
    return x.u;
}
__device__ __forceinline__ float bfu2f(unsigned short u) {
    union { unsigned int i; float f; } x;
    x.i = ((unsigned int)u) << 16;
    return x.f;
}
__device__ __forceinline__ unsigned int pack2bf(float a, float b) {
    union { bf16 h[2]; unsigned int u; } x;
    x.h[0] = (bf16)a; x.h[1] = (bf16)b;
    return x.u;
}
// v_permlane32_swap_b32: a's upper 32 lanes <-> b's lower 32 lanes.
__device__ __forceinline__ void pl32_swap(unsigned int &a, unsigned int &b) {
    asm volatile("v_permlane32_swap_b32 %0, %1" : "+v"(a), "+v"(b));
}

// global -> LDS async copy, 16B per lane. LDS dest must be wave-uniform.
__device__ __forceinline__ void gld_lds16(const void* g, void* l) {
    __builtin_amdgcn_global_load_lds(
        (const __attribute__((address_space(1))) unsigned int*)(uintptr_t)g,
        (__attribute__((address_space(3))) unsigned int*)(unsigned int)(uintptr_t)l,
        16, 0, 0);
}

// ---------------- cast fp32 -> bf16, 8 elems/thread ----------------
__global__ void cast_bf16_kernel(const float* __restrict__ in,
                                 unsigned short* __restrict__ out, int n8) {
    int i = blockIdx.x * blockDim.x + threadIdx.x;
    if (i >= n8) return;
    const f32x4* p = (const f32x4*)(in + (size_t)i * 8);
    f32x4 a = p[0], b = p[1];
    u16x8 o;
    o[0]=f2bfu(a[0]); o[1]=f2bfu(a[1]); o[2]=f2bfu(a[2]); o[3]=f2bfu(a[3]);
    o[4]=f2bfu(b[0]); o[5]=f2bfu(b[1]); o[6]=f2bfu(b[2]); o[7]=f2bfu(b[3]);
    *(u16x8*)(out + (size_t)i * 8) = o;
}

// ---------------- RoPE in-place on q,k sections of qkv [4096][3072] bf16 ----
// q additionally scaled by 0.125*log2(e) (softmax scale folded + exp->exp2).
__global__ void rope_kernel(unsigned short* __restrict__ qkv,
                            const float* __restrict__ cosp,
                            const float* __restrict__ sinp) {
    int tid = blockIdx.x * blockDim.x + threadIdx.x;   // 524288 total
    int i8  = tid & 3;
    int h   = (tid >> 2) & 15;
    int sel = (tid >> 6) & 1;
    int n   = (tid >> 7) & 2047;
    int b   = tid >> 18;
    size_t base = ((size_t)(b*2048 + n))*3072 + sel*1024 + h*64 + i8*8;
    u16x8 x1 = *(u16x8*)(qkv + base);
    u16x8 x2 = *(u16x8*)(qkv + base + 32);
    const f32x4* cp = (const f32x4*)(cosp + n*64 + i8*8);
    const f32x4* sp = (const f32x4*)(sinp + n*64 + i8*8);
    f32x4 c0 = cp[0], c1 = cp[1], s0 = sp[0], s1 = sp[1];
    float scale = sel ? 1.0f : (0.125f * 1.44269504088896f);
    u16x8 o1, o2;
#pragma unroll
    for (int j = 0; j < 8; j++) {
        float cc = (j < 4) ? c0[j] : c1[j-4];
        float ss = (j < 4) ? s0[j] : s1[j-4];
        float a = bfu2f(x1[j]), d = bfu2f(x2[j]);
        o1[j] = f2bfu((a*cc - d*ss) * scale);
        o2[j] = f2bfu((d*cc + a*ss) * scale);
    }
    *(u16x8*)(qkv + base)      = o1;
    *(u16x8*)(qkv + base + 32) = o2;
}

// ---------------- bf16 GEMM: C[M,N] = A[M,K] * B[N,K]^T (both K-contig) -----
// m97 structure: 128x128 tile, BK=32, 4 waves, global_load_lds w=16.
template<int OUT_F32>
__global__ __launch_bounds__(256, 2) void gemm_bt(
    const unsigned short* __restrict__ A, const unsigned short* __restrict__ B,
    void* __restrict__ Cp, const float* __restrict__ bias,
    int M, int N, int K)
{
    __shared__ __align__(16) unsigned short As[128*32];
    __shared__ __align__(16) unsigned short Bs[128*32];
    int nwg  = gridDim.x * gridDim.y;
    int orig = blockIdx.y * gridDim.x + blockIdx.x;
    int qq = nwg >> 3, rr = nwg & 7;
    int xcd = orig & 7, idx = orig >> 3;
    int wg = (xcd < rr) ? (xcd*(qq+1) + idx) : (rr*(qq+1) + (xcd-rr)*qq + idx);
    int bx = wg % gridDim.x, by = wg / gridDim.x;
    int m0 = by * 128, n0 = bx * 128;
    int t = threadIdx.x;
    int w = t >> 6, l = t & 63;
    int c = l & 15, g = l >> 4;
    int wm = (w >> 1) * 64, wn = (w & 1) * 64;

    f32x4 acc[4][4];
#pragma unroll
    for (int i = 0; i < 4; i++)
#pragma unroll
        for (int j = 0; j < 4; j++) acc[i][j] = f32x4{0.f,0.f,0.f,0.f};

    int nkt = K >> 5;
    for (int kt = 0; kt < nkt; ++kt) {
        int k0 = kt << 5;
#pragma unroll
        for (int r2 = 0; r2 < 2; ++r2) {
            int xb = w*2048 + r2*1024;        // byte base of wave chunk
            int x  = xb + l*16;               // per-lane byte
            int row  = x >> 6;                // 64B per row (32 bf16)
            int colu = (x & 63) >> 1;         // ushort col
            gld_lds16(A + (size_t)(m0+row)*K + k0 + colu, (void*)(As + (xb >> 1)));
            gld_lds16(B + (size_t)(n0+row)*K + k0 + colu, (void*)(Bs + (xb >> 1)));
        }
        __syncthreads();
        const unsigned short* Ab = As + wm*32;
        const unsigned short* Bb = Bs + wn*32;
        bf16x8 af[4], bfr[4];
#pragma unroll
        for (int i = 0; i < 4; i++) af[i]  = *(const bf16x8*)(Ab + (i*16+c)*32 + g*8);
#pragma unroll
        for (int i = 0; i < 4; i++) bfr[i] = *(const bf16x8*)(Bb + (i*16+c)*32 + g*8);
#pragma unroll
        for (int i = 0; i < 4; i++)
#pragma unroll
            for (int j = 0; j < 4; j++)
                acc[i][j] = __builtin_amdgcn_mfma_f32_16x16x32_bf16(af[i], bfr[j], acc[i][j], 0, 0, 0);
        __syncthreads();
    }
#pragma unroll
    for (int i = 0; i < 4; i++)
#pragma unroll
        for (int j = 0; j < 4; j++)
#pragma unroll
            for (int e = 0; e < 4; e++) {
                int row = m0 + wm + i*16 + g*4 + e;
                int col = n0 + wn + j*16 + c;
                float v = acc[i][j][e];
                if (bias) v += bias[col];
                if (OUT_F32) ((float*)Cp)[(size_t)row*N + col] = v;
                else ((unsigned short*)Cp)[(size_t)row*N + col] = f2bfu(v);
            }
}

// ---------------- flash attention, 32x32 MFMA + permlane32_swap -------------
// grid (16 q-tiles, 32 bh). block 256 = 4 waves; wave owns 32 q rows.
// S^T = mfma32(K, Q): lane holds S^T[kv-rows][q=lane&31]; P^T PV-B-frags are
// assembled with 2 permlane32_swap per k-chunk (no LDS round-trip/bpermute).
// out^T = mfma32(V^T, P^T). exp2-based softmax (log2e folded into q scale).
__global__ __launch_bounds__(256, 2) void attn_kernel(
    const unsigned short* __restrict__ qkv, unsigned short* __restrict__ outp)
{
    __shared__ __align__(16) unsigned short Ks[64*64];  // K tile, swizzled
    __shared__ __align__(16) unsigned short Vt[64*64];  // V^T tile, swizzled
    int bh = blockIdx.y;
    int b = bh >> 4, h = bh & 15;
    int q0 = blockIdx.x << 7;
    int t = threadIdx.x;
    int w = t >> 6, l = t & 63;
    int q = l & 31, hi = l >> 5;
    int qw = q0 + w*32;
    size_t bh_base = ((size_t)b*2048)*3072 + (size_t)h*64;

    // Q B-frags: qf[dc] = Q[qw+q][dc*16 + hi*8 .. +7]
    bf16x8 qf[4];
#pragma unroll
    for (int dc = 0; dc < 4; dc++)
        qf[dc] = *(const bf16x8*)(qkv + bh_base + (size_t)(qw + q)*3072 + dc*16 + hi*8);

    f32x16 oacc[2];
#pragma unroll
    for (int e = 0; e < 16; e++) { oacc[0][e] = 0.f; oacc[1][e] = 0.f; }
    float lsum = 0.f;

    for (int kvt = 0; kvt < 32; ++kvt) {
        int kv0 = kvt << 6;
        // stage K tile via global_load_lds, source pre-swizzled (read-side XOR)
#pragma unroll
        for (int r2 = 0; r2 < 2; ++r2) {
            int xb = w*2048 + r2*1024;
            int x  = xb + l*16;
            int row  = x >> 7;                 // 128B rows
            int colb = x & 127;
            int scolb = colb ^ ((row & 7) << 4);
            gld_lds16(qkv + bh_base + 1024 + (size_t)(kv0 + row)*3072 + (scolb >> 1),
                      (void*)(Ks + (xb >> 1)));
        }
        // stage V^T (reg transpose), swizzled
        {
            int p  = t >> 3;
            int hb = (t & 7) << 3;
            const unsigned short* src = qkv + bh_base + 2048 + (size_t)(kv0 + 2*p)*3072 + hb;
            u16x8 v0 = *(const u16x8*)src;
            u16x8 v1 = *(const u16x8*)(src + 3072);
#pragma unroll
            for (int e = 0; e < 8; e++) {
                int hd = hb + e;
                int colb = (4*p) ^ ((((hd) ^ (hd >> 3)) & 7) << 4);
                *(unsigned int*)((char*)Vt + hd*128 + colb) =
                    (unsigned int)v0[e] | ((unsigned int)v1[e] << 16);
            }
        }
        __syncthreads();

#pragma unroll
        for (int sblk = 0; sblk < 2; ++sblk) {
            // S^T block [32 kv][32 q] = K * Q^T : 4 MFMA over d
            f32x16 st;
#pragma unroll
            for (int e = 0; e < 16; e++) st[e] = 0.f;
            int krow = sblk*32 + q;
            int ksw = (krow & 7) << 4;
#pragma unroll
            for (int dc = 0; dc < 4; ++dc) {
                bf16x8 kf = *(const bf16x8*)((const char*)Ks + krow*128 + ((dc*32 + hi*16) ^ ksw));
                st = __builtin_amdgcn_mfma_f32_32x32x16_bf16(kf, qf[dc], st, 0, 0, 0);
            }
            // softmax: P = exp2(S') (log2e pre-folded); pack pairs; row-sum
            unsigned int wds[8];
#pragma unroll
            for (int m = 0; m < 8; m++) {
                float p0 = __builtin_amdgcn_exp2f(st[2*m]);
                float p1 = __builtin_amdgcn_exp2f(st[2*m+1]);
                lsum += p0 + p1;
                wds[m] = pack2bf(p0, p1);
            }
            // PV: for each 16-kv chunk assemble P^T B-frag via 2 swaps, 2 MFMA
#pragma unroll
            for (int half = 0; half < 2; ++half) {
                unsigned int a0 = wds[half*4 + 0], b0 = wds[half*4 + 2];
                unsigned int a1 = wds[half*4 + 1], b1 = wds[half*4 + 3];
                pl32_swap(a0, b0);
                pl32_swap(a1, b1);
                union { unsigned int u[4]; bf16x8 v; } pf;
                pf.u[0] = a0; pf.u[1] = a1; pf.u[2] = b0; pf.u[3] = b1;
                int kc = sblk*2 + half;
#pragma unroll
                for (int hdblk = 0; hdblk < 2; ++hdblk) {
                    int hd = hdblk*32 + q;
                    int vsw = ((hd ^ (hd >> 3)) & 7) << 4;
                    bf16x8 vf = *(const bf16x8*)((const char*)Vt + hd*128 + ((kc*32 + hi*16) ^ vsw));
                    oacc[hdblk] = __builtin_amdgcn_mfma_f32_32x32x16_bf16(vf, pf.v, oacc[hdblk], 0, 0, 0);
                }
            }
        }
        __syncthreads();
    }
    // finalize: full column sum needs partner half (rows +-4), then scale+store
    float ltot = lsum + __shfl_xor(lsum, 32, 64);
    float rinv = 1.0f / ltot;
    // lane holds O^T[hd][q], hd = (reg&3) + 8*(reg>>2) + 4*hi + 32*hdblk.
    // regs within a quad are consecutive hd -> 8B packed stores.
    size_t orow = (size_t)(b*2048 + qw + q) * 1024 + h*64;
#pragma unroll
    for (int hdblk = 0; hdblk < 2; ++hdblk)
#pragma unroll
        for (int quad = 0; quad < 4; ++quad) {
            u16x4 o4;
#pragma unroll
            for (int j = 0; j < 4; j++)
                o4[j] = f2bfu(oacc[hdblk][quad*4 + j] * rinv);
            *(u16x4*)(outp + orow + hdblk*32 + quad*8 + hi*4) = o4;
        }
}

// ---------------- launch ----------------------------------------------------
extern "C" void kernel_launch(void* const* d_in, const int* in_sizes, int n_in,
                              void* d_out, int out_size, void* d_ws, size_t ws_size,
                              hipStream_t stream) {
    const float* x      = (const float*)d_in[0];
    const float* cosp   = (const float*)d_in[1];
    const float* sinp   = (const float*)d_in[2];
    const float* qkv_w  = (const float*)d_in[3];
    const float* proj_w = (const float*)d_in[4];
    const float* proj_b = (const float*)d_in[5];

    char* ws = (char*)d_ws;
    // ws layout (40 MB total):
    // [0,8MB)   xb   : x in bf16 [4096][1024]   (reused as attn output later)
    // [8,14MB)  wqkvb: qkv_w bf16 [3072][1024]
    // [14,16MB) wprojb: proj_w bf16 [1024][1024]
    // [16,40MB) qkvb : qkv bf16 [4096][3072]
    unsigned short* xb     = (unsigned short*)(ws);
    unsigned short* wqkvb  = (unsigned short*)(ws + (size_t)(8u << 20));
    unsigned short* wprojb = (unsigned short*)(ws + (size_t)(14u << 20));
    unsigned short* qkvb   = (unsigned short*)(ws + (size_t)(16u << 20));
    unsigned short* attno  = xb;

    cast_bf16_kernel<<<2048, 256, 0, stream>>>(x, xb, 524288);
    cast_bf16_kernel<<<1536, 256, 0, stream>>>(qkv_w, wqkvb, 393216);
    cast_bf16_kernel<<<512, 256, 0, stream>>>(proj_w, wprojb, 131072);

    gemm_bt<0><<<dim3(24, 32), 256, 0, stream>>>(xb, wqkvb, (void*)qkvb, nullptr, 4096, 3072, 1024);
    rope_kernel<<<2048, 256, 0, stream>>>(qkvb, cosp, sinp);
    attn_kernel<<<dim3(16, 32), 256, 0, stream>>>(qkvb, attno);
    gemm_bt<1><<<dim3(8, 32), 256, 0, stream>>>(attno, wprojb, d_out, proj_b, 4096, 1024, 1024);
}

// Round 7
// 134.912 us; speedup vs baseline: 1.1707x; 1.0761x over previous
//
#include <hip/hip_runtime.h>
#include <stdint.h>

typedef __bf16 bf16;
typedef bf16 bf16x8 __attribute__((ext_vector_type(8)));
typedef float f32x4 __attribute__((ext_vector_type(4)));
typedef float f32x16 __attribute__((ext_vector_type(16)));
typedef unsigned short u16x8 __attribute__((ext_vector_type(8)));
typedef unsigned short u16x4 __attribute__((ext_vector_type(4)));

__device__ __forceinline__ unsigned short f2bfu(float f) {
    union { bf16 h; unsigned short u; } x;
    x.h = (bf16)f;
    return x.u;
}
__device__ __forceinline__ float bfu2f(unsigned short u) {
    union { unsigned int i; float f; } x;
    x.i = ((unsigned int)u) << 16;
    return x.f;
}
__device__ __forceinline__ unsigned int pack2bf(float a, float b) {
    union { bf16 h[2]; unsigned int u; } x;
    x.h[0] = (bf16)a; x.h[1] = (bf16)b;
    return x.u;
}
// v_permlane32_swap_b32: a's upper 32 lanes <-> b's lower 32 lanes.
__device__ __forceinline__ void pl32_swap(unsigned int &a, unsigned int &b) {
    asm volatile("v_permlane32_swap_b32 %0, %1" : "+v"(a), "+v"(b));
}

// global -> LDS async copy, 16B per lane. LDS dest must be wave-uniform.
__device__ __forceinline__ void gld_lds16(const void* g, void* l) {
    __builtin_amdgcn_global_load_lds(
        (const __attribute__((address_space(1))) unsigned int*)(uintptr_t)g,
        (__attribute__((address_space(3))) unsigned int*)(unsigned int)(uintptr_t)l,
        16, 0, 0);
}

// ---------------- cast fp32 -> bf16, 8 elems/thread ----------------
__global__ void cast_bf16_kernel(const float* __restrict__ in,
                                 unsigned short* __restrict__ out, int n8) {
    int i = blockIdx.x * blockDim.x + threadIdx.x;
    if (i >= n8) return;
    const f32x4* p = (const f32x4*)(in + (size_t)i * 8);
    f32x4 a = p[0], b = p[1];
    u16x8 o;
    o[0]=f2bfu(a[0]); o[1]=f2bfu(a[1]); o[2]=f2bfu(a[2]); o[3]=f2bfu(a[3]);
    o[4]=f2bfu(b[0]); o[5]=f2bfu(b[1]); o[6]=f2bfu(b[2]); o[7]=f2bfu(b[3]);
    *(u16x8*)(out + (size_t)i * 8) = o;
}

// ---------------- RoPE in-place on q,k sections of qkv [4096][3072] bf16 ----
// q additionally scaled by 0.125*log2(e) (softmax scale folded + exp->exp2).
__global__ void rope_kernel(unsigned short* __restrict__ qkv,
                            const float* __restrict__ cosp,
                            const float* __restrict__ sinp) {
    int tid = blockIdx.x * blockDim.x + threadIdx.x;   // 524288 total
    int i8  = tid & 3;
    int h   = (tid >> 2) & 15;
    int sel = (tid >> 6) & 1;
    int n   = (tid >> 7) & 2047;
    int b   = tid >> 18;
    size_t base = ((size_t)(b*2048 + n))*3072 + sel*1024 + h*64 + i8*8;
    u16x8 x1 = *(u16x8*)(qkv + base);
    u16x8 x2 = *(u16x8*)(qkv + base + 32);
    const f32x4* cp = (const f32x4*)(cosp + n*64 + i8*8);
    const f32x4* sp = (const f32x4*)(sinp + n*64 + i8*8);
    f32x4 c0 = cp[0], c1 = cp[1], s0 = sp[0], s1 = sp[1];
    float scale = sel ? 1.0f : (0.125f * 1.44269504088896f);
    u16x8 o1, o2;
#pragma unroll
    for (int j = 0; j < 8; j++) {
        float cc = (j < 4) ? c0[j] : c1[j-4];
        float ss = (j < 4) ? s0[j] : s1[j-4];
        float a = bfu2f(x1[j]), d = bfu2f(x2[j]);
        o1[j] = f2bfu((a*cc - d*ss) * scale);
        o2[j] = f2bfu((d*cc + a*ss) * scale);
    }
    *(u16x8*)(qkv + base)      = o1;
    *(u16x8*)(qkv + base + 32) = o2;
}

// ---------------- bf16 GEMM: C[M,N] = A[M,K] * B[N,K]^T (both K-contig) -----
// T3-lite: double-buffered LDS, ONE barrier per K-step, stage(t+1) issued
// AFTER the barrier so gld_lds stays in flight through compute(t).
template<int OUT_F32>
__global__ __launch_bounds__(256, 2) void gemm_bt(
    const unsigned short* __restrict__ A, const unsigned short* __restrict__ B,
    void* __restrict__ Cp, const float* __restrict__ bias,
    int M, int N, int K)
{
    __shared__ __align__(16) unsigned short As[2][128*32];
    __shared__ __align__(16) unsigned short Bs[2][128*32];
    int nwg  = gridDim.x * gridDim.y;
    int orig = blockIdx.y * gridDim.x + blockIdx.x;
    int qq = nwg >> 3, rr = nwg & 7;
    int xcd = orig & 7, idx = orig >> 3;
    int wg = (xcd < rr) ? (xcd*(qq+1) + idx) : (rr*(qq+1) + (xcd-rr)*qq + idx);
    int bx = wg % gridDim.x, by = wg / gridDim.x;
    int m0 = by * 128, n0 = bx * 128;
    int t = threadIdx.x;
    int w = t >> 6, l = t & 63;
    int c = l & 15, g = l >> 4;
    int wm = (w >> 1) * 64, wn = (w & 1) * 64;

    auto stage = [&](int kt, int bsel) {
#pragma unroll
        for (int r2 = 0; r2 < 2; ++r2) {
            int xb = w*2048 + r2*1024;        // byte base of wave chunk
            int x  = xb + l*16;               // per-lane byte
            int row  = x >> 6;                // 64B per row (32 bf16)
            int colu = (x & 63) >> 1;         // ushort col
            int k0 = kt << 5;
            gld_lds16(A + (size_t)(m0+row)*K + k0 + colu, (void*)(As[bsel] + (xb >> 1)));
            gld_lds16(B + (size_t)(n0+row)*K + k0 + colu, (void*)(Bs[bsel] + (xb >> 1)));
        }
    };

    f32x4 acc[4][4];
#pragma unroll
    for (int i = 0; i < 4; i++)
#pragma unroll
        for (int j = 0; j < 4; j++) acc[i][j] = f32x4{0.f,0.f,0.f,0.f};

    int nkt = K >> 5;
    stage(0, 0);
    int cur = 0;
    for (int kt = 0; kt < nkt; ++kt) {
        __syncthreads();                      // drains stage(kt); frees buf cur^1
        if (kt + 1 < nkt) stage(kt + 1, cur ^ 1);   // in flight through compute
        const unsigned short* Ab = As[cur] + wm*32;
        const unsigned short* Bb = Bs[cur] + wn*32;
        bf16x8 af[4], bfr[4];
#pragma unroll
        for (int i = 0; i < 4; i++) af[i]  = *(const bf16x8*)(Ab + (i*16+c)*32 + g*8);
#pragma unroll
        for (int i = 0; i < 4; i++) bfr[i] = *(const bf16x8*)(Bb + (i*16+c)*32 + g*8);
#pragma unroll
        for (int i = 0; i < 4; i++)
#pragma unroll
            for (int j = 0; j < 4; j++)
                acc[i][j] = __builtin_amdgcn_mfma_f32_16x16x32_bf16(af[i], bfr[j], acc[i][j], 0, 0, 0);
        cur ^= 1;
    }
#pragma unroll
    for (int i = 0; i < 4; i++)
#pragma unroll
        for (int j = 0; j < 4; j++)
#pragma unroll
            for (int e = 0; e < 4; e++) {
                int row = m0 + wm + i*16 + g*4 + e;
                int col = n0 + wn + j*16 + c;
                float v = acc[i][j][e];
                if (bias) v += bias[col];
                if (OUT_F32) ((float*)Cp)[(size_t)row*N + col] = v;
                else ((unsigned short*)Cp)[(size_t)row*N + col] = f2bfu(v);
            }
}

// ---------------- flash attention, 32x32 MFMA + permlane32_swap -------------
// grid (16 q-tiles, 32 bh). block 256 = 4 waves; wave owns 32 q rows.
// T3-lite pipeline: double-buffered K/V LDS, ONE barrier per kv-tile;
// stage(t+1) (gld_lds K + global V->regs) issued AFTER the barrier so the
// loads stay in flight through compute(t). V ds_write happens at top of the
// next iteration (regs had a full compute phase to arrive).
__global__ __launch_bounds__(256, 2) void attn_kernel(
    const unsigned short* __restrict__ qkv, unsigned short* __restrict__ outp)
{
    __shared__ __align__(16) unsigned short Ks[2][64*64];  // K tiles, swizzled
    __shared__ __align__(16) unsigned short Vt[2][64*64];  // V^T tiles, swizzled
    int bh = blockIdx.y;
    int b = bh >> 4, h = bh & 15;
    int q0 = blockIdx.x << 7;
    int t = threadIdx.x;
    int w = t >> 6, l = t & 63;
    int q = l & 31, hi = l >> 5;
    int qw = q0 + w*32;
    size_t bh_base = ((size_t)b*2048)*3072 + (size_t)h*64;

    auto stageK = [&](int kv0, int bsel) {
#pragma unroll
        for (int r2 = 0; r2 < 2; ++r2) {
            int xb = w*2048 + r2*1024;
            int x  = xb + l*16;
            int row  = x >> 7;                 // 128B rows
            int scolb = (x & 127) ^ ((row & 7) << 4);
            gld_lds16(qkv + bh_base + 1024 + (size_t)(kv0 + row)*3072 + (scolb >> 1),
                      (void*)(Ks[bsel] + (xb >> 1)));
        }
    };
    auto loadV = [&](int kv0, u16x8 &v0, u16x8 &v1) {
        int p  = t >> 3;
        int hb = (t & 7) << 3;
        const unsigned short* src = qkv + bh_base + 2048 + (size_t)(kv0 + 2*p)*3072 + hb;
        v0 = *(const u16x8*)src;
        v1 = *(const u16x8*)(src + 3072);
    };
    auto writeV = [&](const u16x8 &v0, const u16x8 &v1, int bsel) {
        int p  = t >> 3;
        int hb = (t & 7) << 3;
#pragma unroll
        for (int e = 0; e < 8; e++) {
            int hd = hb + e;
            int colb = (4*p) ^ ((((hd) ^ (hd >> 3)) & 7) << 4);
            *(unsigned int*)((char*)Vt[bsel] + hd*128 + colb) =
                (unsigned int)v0[e] | ((unsigned int)v1[e] << 16);
        }
    };

    // Q B-frags: qf[dc] = Q[qw+q][dc*16 + hi*8 .. +7]
    bf16x8 qf[4];
#pragma unroll
    for (int dc = 0; dc < 4; dc++)
        qf[dc] = *(const bf16x8*)(qkv + bh_base + (size_t)(qw + q)*3072 + dc*16 + hi*8);

    f32x16 oacc[2];
#pragma unroll
    for (int e = 0; e < 16; e++) { oacc[0][e] = 0.f; oacc[1][e] = 0.f; }
    float lsum = 0.f;

    u16x8 vc0, vc1, vn0, vn1;
    stageK(0, 0);
    loadV(0, vc0, vc1);
    int cur = 0;

    for (int kvt = 0; kvt < 32; ++kvt) {
        writeV(vc0, vc1, cur);                 // waits V(t) regs (counted vmcnt)
        __syncthreads();                       // drains K(t) gld_lds + V writes;
                                               // all waves done compute(t-1)
        if (kvt < 31) {
            int kv0n = (kvt + 1) << 6;
            stageK(kv0n, cur ^ 1);             // in flight through compute(t)
            loadV(kv0n, vn0, vn1);
        }
        const char* ksb = (const char*)Ks[cur];
        const char* vtb = (const char*)Vt[cur];

#pragma unroll
        for (int sblk = 0; sblk < 2; ++sblk) {
            // S^T block [32 kv][32 q] = K * Q^T : 4 MFMA over d
            f32x16 st;
#pragma unroll
            for (int e = 0; e < 16; e++) st[e] = 0.f;
            int krow = sblk*32 + q;
            int ksw = (krow & 7) << 4;
#pragma unroll
            for (int dc = 0; dc < 4; ++dc) {
                bf16x8 kf = *(const bf16x8*)(ksb + krow*128 + ((dc*32 + hi*16) ^ ksw));
                st = __builtin_amdgcn_mfma_f32_32x32x16_bf16(kf, qf[dc], st, 0, 0, 0);
            }
            // softmax: P = exp2(S') (log2e pre-folded); pack pairs; row-sum
            unsigned int wds[8];
#pragma unroll
            for (int m = 0; m < 8; m++) {
                float p0 = __builtin_amdgcn_exp2f(st[2*m]);
                float p1 = __builtin_amdgcn_exp2f(st[2*m+1]);
                lsum += p0 + p1;
                wds[m] = pack2bf(p0, p1);
            }
            // PV: for each 16-kv chunk assemble P^T B-frag via 2 swaps, 2 MFMA
#pragma unroll
            for (int half = 0; half < 2; ++half) {
                unsigned int a0 = wds[half*4 + 0], b0 = wds[half*4 + 2];
                unsigned int a1 = wds[half*4 + 1], b1 = wds[half*4 + 3];
                pl32_swap(a0, b0);
                pl32_swap(a1, b1);
                union { unsigned int u[4]; bf16x8 v; } pf;
                pf.u[0] = a0; pf.u[1] = a1; pf.u[2] = b0; pf.u[3] = b1;
                int kc = sblk*2 + half;
#pragma unroll
                for (int hdblk = 0; hdblk < 2; ++hdblk) {
                    int hd = hdblk*32 + q;
                    int vsw = ((hd ^ (hd >> 3)) & 7) << 4;
                    bf16x8 vf = *(const bf16x8*)(vtb + hd*128 + ((kc*32 + hi*16) ^ vsw));
                    oacc[hdblk] = __builtin_amdgcn_mfma_f32_32x32x16_bf16(vf, pf.v, oacc[hdblk], 0, 0, 0);
                }
            }
        }
        vc0 = vn0; vc1 = vn1;
        cur ^= 1;
    }
    // finalize: full column sum needs partner half (rows +-4), then scale+store
    float ltot = lsum + __shfl_xor(lsum, 32, 64);
    float rinv = 1.0f / ltot;
    // lane holds O^T[hd][q], hd = (reg&3) + 8*(reg>>2) + 4*hi + 32*hdblk.
    // regs within a quad are consecutive hd -> 8B packed stores.
    size_t orow = (size_t)(b*2048 + qw + q) * 1024 + h*64;
#pragma unroll
    for (int hdblk = 0; hdblk < 2; ++hdblk)
#pragma unroll
        for (int quad = 0; quad < 4; ++quad) {
            u16x4 o4;
#pragma unroll
            for (int j = 0; j < 4; j++)
                o4[j] = f2bfu(oacc[hdblk][quad*4 + j] * rinv);
            *(u16x4*)(outp + orow + hdblk*32 + quad*8 + hi*4) = o4;
        }
}

// ---------------- launch ----------------------------------------------------
extern "C" void kernel_launch(void* const* d_in, const int* in_sizes, int n_in,
                              void* d_out, int out_size, void* d_ws, size_t ws_size,
                              hipStream_t stream) {
    const float* x      = (const float*)d_in[0];
    const float* cosp   = (const float*)d_in[1];
    const float* sinp   = (const float*)d_in[2];
    const float* qkv_w  = (const float*)d_in[3];
    const float* proj_w = (const float*)d_in[4];
    const float* proj_b = (const float*)d_in[5];

    char* ws = (char*)d_ws;
    // ws layout (40 MB total):
    // [0,8MB)   xb   : x in bf16 [4096][1024]   (reused as attn output later)
    // [8,14MB)  wqkvb: qkv_w bf16 [3072][1024]
    // [14,16MB) wprojb: proj_w bf16 [1024][1024]
    // [16,40MB) qkvb : qkv bf16 [4096][3072]
    unsigned short* xb     = (unsigned short*)(ws);
    unsigned short* wqkvb  = (unsigned short*)(ws + (size_t)(8u << 20));
    unsigned short* wprojb = (unsigned short*)(ws + (size_t)(14u << 20));
    unsigned short* qkvb   = (unsigned short*)(ws + (size_t)(16u << 20));
    unsigned short* attno  = xb;

    cast_bf16_kernel<<<2048, 256, 0, stream>>>(x, xb, 524288);
    cast_bf16_kernel<<<1536, 256, 0, stream>>>(qkv_w, wqkvb, 393216);
    cast_bf16_kernel<<<512, 256, 0, stream>>>(proj_w, wprojb, 131072);

    gemm_bt<0><<<dim3(24, 32), 256, 0, stream>>>(xb, wqkvb, (void*)qkvb, nullptr, 4096, 3072, 1024);
    rope_kernel<<<2048, 256, 0, stream>>>(qkvb, cosp, sinp);
    attn_kernel<<<dim3(16, 32), 256, 0, stream>>>(qkvb, attno);
    gemm_bt<1><<<dim3(8, 32), 256, 0, stream>>>(attno, wprojb, d_out, proj_b, 4096, 1024, 1024);
}